// Round 2
// baseline (2468.525 us; speedup 1.0000x reference)
//
#include <hip/hip_runtime.h>

#define NTOK 49
#define CDIM 384
#define HEADS 12
#define HD 32
#define NWIN 64
#define NQKV 1152
#define SCALE 0.17677669529663687f  // 32^-0.5

typedef __attribute__((ext_vector_type(8))) __bf16 bf16x8;
typedef __attribute__((ext_vector_type(4))) float f32x4;

// workspace offsets (bytes), all 256-aligned
#define OFF_WQKVT   0ull                 // 1152*384 bf16 = 884736
#define OFF_WOUTT   884736ull            // 384*384 bf16  = 294912
#define OFF_ADDEND  1179648ull           // 64*12*49*49 f32 = 7375872
#define OFF_ATTNOUT 8555520ull           // B*49*384 bf16 = 154140672

// ---------------- prep kernels ----------------

__global__ void prep_weights(const float* __restrict__ Wqkv, const float* __restrict__ Wout,
                             __bf16* __restrict__ WqkvT, __bf16* __restrict__ WoutT) {
    int idx = blockIdx.x * 256 + threadIdx.x;
    if (idx < NQKV * CDIM) {
        int n = idx / CDIM, k = idx % CDIM;
        WqkvT[idx] = (__bf16)Wqkv[(size_t)k * NQKV + n];
    }
    if (idx < CDIM * CDIM) {
        int n = idx / CDIM, k = idx % CDIM;
        WoutT[idx] = (__bf16)Wout[(size_t)k * CDIM + n];
    }
}

__global__ void prep_addend(const float* __restrict__ rpb, const int* __restrict__ rel,
                            const float* __restrict__ mask, float* __restrict__ addend) {
    int idx = blockIdx.x * 256 + threadIdx.x;
    if (idx >= NWIN * HEADS * NTOK * NTOK) return;
    int mn = idx % (NTOK * NTOK);
    int h  = (idx / (NTOK * NTOK)) % HEADS;
    int w  = idx / (NTOK * NTOK * HEADS);
    addend[idx] = rpb[rel[mn] * HEADS + h] + mask[(size_t)w * NTOK * NTOK + mn];
}

// ---------------- fused qkv + attention ----------------
// one block per window; 512 threads = 8 waves; 6 groups of 2 heads.
// All MFMA operands stored in LDS as fragment-linear: frag[tile][lane][8] -> reads are base+lane*16.
// LDS: xs 49152 + qk/ps union 16384 + vt 8192 = 73728 B -> 2 blocks/CU.

__global__ __launch_bounds__(512, 4) void fused_qkv_attn(
    const float* __restrict__ x, const float* __restrict__ bqkv,
    const __bf16* __restrict__ WqkvT, const float* __restrict__ addend,
    __bf16* __restrict__ attnout)
{
    __shared__ __attribute__((aligned(16))) __bf16 xs[4 * 12 * 512];   // x frags [mt][kb][slot][8], slot = lane^(kb&7)
    __shared__ __attribute__((aligned(16))) __bf16 qkps[8192];         // q: [0,4096) [hl][mt][lane][8]; k: [4096,8192) [hl][nt][lane][8]
                                                                       // ps overlays all: [hl][mt][kb][lane][8]
    __shared__ __attribute__((aligned(16))) __bf16 vt[2 * 2 * 2 * 512];// [hl][dt][kb][lane][8]

    const int b    = blockIdx.x;
    const int tid  = threadIdx.x;
    const int wave = tid >> 6, lane = tid & 63;
    const int l15  = lane & 15, l4 = lane >> 4;
    const int w    = b & (NWIN - 1);

    // ---- phase 0: stage x -> bf16 fragment-linear LDS ----
    {
        // zero pad rows 49..63 (mt=3, slot row-part != 0)
        for (int i = tid; i < 12 * 64; i += 512) {
            int kb = i >> 6, lp = i & 63;
            if (lp & 15) {
                int slot = lp ^ (kb & 7);
                *reinterpret_cast<int4*>(&xs[((36 + kb) * 64 + slot) * 8]) = int4{0, 0, 0, 0};
            }
        }
        const float* xw = x + (size_t)b * NTOK * CDIM;
        for (int i = tid; i < NTOK * CDIM / 4; i += 512) {
            float4 v = reinterpret_cast<const float4*>(xw)[i];
            int e = i * 4;
            int row = e / CDIM, c = e % CDIM;
            int mt = row >> 4, kb = c >> 5;
            int lp = (row & 15) + 16 * ((c & 31) >> 3);
            int slot = lp ^ (kb & 7);
            union { __bf16 h[4]; uint2 u; } t;
            t.h[0] = (__bf16)v.x; t.h[1] = (__bf16)v.y; t.h[2] = (__bf16)v.z; t.h[3] = (__bf16)v.w;
            *reinterpret_cast<uint2*>(&xs[((mt * 12 + kb) * 64 + slot) * 8 + (c & 7)]) = t.u;
        }
    }
    __syncthreads();

    for (int g = 0; g < 6; ++g) {
        // ---- QKV gemm: 48 units (12 ncol-tiles x 4 mt), 6 per wave ----
        {
            f32x4 acc[6] = {};
            const __bf16* bptr[6];
            int um[6];
#pragma unroll
            for (int i = 0; i < 6; ++i) {
                int u = wave + 8 * i;
                int mt = u & 3, n = u >> 2;          // n = hl*6 + which*2 + sub
                int hl = n / 6, rem = n % 6;
                int which = rem >> 1, sub = rem & 1;
                int h = g * 2 + hl;
                int wcol = which * CDIM + h * HD + sub * 16 + l15;
                bptr[i] = WqkvT + (size_t)wcol * CDIM + l4 * 8;
                um[i] = mt;
            }
            for (int kb = 0; kb < 12; ++kb) {
                int slot = lane ^ (kb & 7);
                bf16x8 bf[6], af[6];
#pragma unroll
                for (int i = 0; i < 6; ++i)
                    bf[i] = *reinterpret_cast<const bf16x8*>(bptr[i] + kb * 32);
#pragma unroll
                for (int i = 0; i < 6; ++i)
                    af[i] = *reinterpret_cast<const bf16x8*>(&xs[((um[i] * 12 + kb) * 64 + slot) * 8]);
#pragma unroll
                for (int i = 0; i < 6; ++i)
                    acc[i] = __builtin_amdgcn_mfma_f32_16x16x32_bf16(af[i], bf[i], acc[i], 0, 0, 0);
            }
            // write to fragment-linear q/k/vt
#pragma unroll
            for (int i = 0; i < 6; ++i) {
                int u = wave + 8 * i;
                int mt = u & 3, n = u >> 2;
                int hl = n / 6, rem = n % 6;
                int which = rem >> 1, sub = rem & 1;
                int h = g * 2 + hl;
                int wcol = which * CDIM + h * HD + sub * 16 + l15;
                float bias = bqkv[wcol];
                float scl = (which == 0) ? SCALE : 1.0f;
#pragma unroll
                for (int r = 0; r < 4; ++r) {
                    float vv = (acc[i][r] + bias) * scl;
                    __bf16 bv = (__bf16)vv;
                    int mrow = l4 * 4 + r;   // row within 16-tile
                    if (which == 2) {
                        int tok = mt * 16 + mrow;
                        int kb2 = tok >> 5;
                        int lp = l15 + 16 * ((tok & 31) >> 3);
                        vt[(((hl * 2 + sub) * 2 + kb2) * 64 + lp) * 8 + (tok & 7)] = bv;
                    } else {
                        int lp = mrow + 16 * (sub * 2 + (l15 >> 3));
                        int base = (which == 1) ? 4096 : 0;
                        qkps[base + ((hl * 4 + mt) * 64 + lp) * 8 + (l15 & 7)] = bv;
                    }
                }
            }
        }
        __syncthreads();   // bar A: q/k/vt ready

        // ---- attention: wave -> head hl = wave>>2, m-tile mt = wave&3 ----
        {
            int hl = wave >> 2, mt = wave & 3;
            int h = g * 2 + hl;

            // S = q k^T  (K=32 -> 1 MFMA per n-tile)
            bf16x8 aq = *reinterpret_cast<const bf16x8*>(&qkps[(hl * 4 + mt) * 512 + lane * 8]);
            f32x4 s[4];
#pragma unroll
            for (int nt = 0; nt < 4; ++nt) {
                bf16x8 bk = *reinterpret_cast<const bf16x8*>(&qkps[4096 + (hl * 4 + nt) * 512 + lane * 8]);
                f32x4 z = {};
                s[nt] = __builtin_amdgcn_mfma_f32_16x16x32_bf16(aq, bk, z, 0, 0, 0);
            }
            __syncthreads();   // bar B: all q/k reads done; ps may overwrite

            const float* add_h = addend + (size_t)(w * HEADS + h) * (NTOK * NTOK);
#pragma unroll
            for (int r = 0; r < 4; ++r) {
                int m = mt * 16 + l4 * 4 + r;
                float vals[4];
#pragma unroll
                for (int nt = 0; nt < 4; ++nt) {
                    int n = nt * 16 + l15;
                    float sv = s[nt][r];
                    if (n < NTOK) {
                        if (m < NTOK) sv += add_h[m * NTOK + n];
                    } else {
                        sv = -1e30f;
                    }
                    vals[nt] = sv;
                }
                float mx = fmaxf(fmaxf(vals[0], vals[1]), fmaxf(vals[2], vals[3]));
                mx = fmaxf(mx, __shfl_xor(mx, 1));
                mx = fmaxf(mx, __shfl_xor(mx, 2));
                mx = fmaxf(mx, __shfl_xor(mx, 4));
                mx = fmaxf(mx, __shfl_xor(mx, 8));
                float e0 = __expf(vals[0] - mx);
                float e1 = __expf(vals[1] - mx);
                float e2 = __expf(vals[2] - mx);
                float e3 = __expf(vals[3] - mx);
                float sum = (e0 + e1) + (e2 + e3);
                sum += __shfl_xor(sum, 1);
                sum += __shfl_xor(sum, 2);
                sum += __shfl_xor(sum, 4);
                sum += __shfl_xor(sum, 8);
                float inv = 1.0f / sum;
                float ev[4] = {e0, e1, e2, e3};
#pragma unroll
                for (int nt = 0; nt < 4; ++nt) {
                    int lp = (l4 * 4 + r) + 16 * ((nt & 1) * 2 + (l15 >> 3));
                    int kb = nt >> 1;
                    qkps[(((hl * 4 + mt) * 2 + kb) * 64 + lp) * 8 + (l15 & 7)] = (__bf16)(ev[nt] * inv);
                }
            }

            // PV (same wave reads its own ps region; compiler inserts lgkmcnt)
            f32x4 o[2] = {};
#pragma unroll
            for (int kb = 0; kb < 2; ++kb) {
                bf16x8 ap = *reinterpret_cast<const bf16x8*>(&qkps[((hl * 4 + mt) * 2 + kb) * 512 + lane * 8]);
#pragma unroll
                for (int dt = 0; dt < 2; ++dt) {
                    bf16x8 bv = *reinterpret_cast<const bf16x8*>(&vt[((hl * 2 + dt) * 2 + kb) * 512 + lane * 8]);
                    o[dt] = __builtin_amdgcn_mfma_f32_16x16x32_bf16(ap, bv, o[dt], 0, 0, 0);
                }
            }
#pragma unroll
            for (int dt = 0; dt < 2; ++dt) {
                int col = h * HD + dt * 16 + l15;
#pragma unroll
                for (int r = 0; r < 4; ++r) {
                    int tok = mt * 16 + l4 * 4 + r;
                    if (tok < NTOK)
                        attnout[((size_t)b * NTOK + tok) * CDIM + col] = (__bf16)o[dt][r];
                }
            }
        }
        __syncthreads();   // bar C: ps/vt reads done before next group's writes
    }
}

// ---------------- out projection: [M=B*49, 384] @ [384,384] + b ----------------
// block: 64 rows, 256 threads = 4 waves; wave w covers n-tiles 6w..6w+5
// A staged fragment-linear (conflict-free reads).

__global__ __launch_bounds__(256, 3) void out_proj(
    const __bf16* __restrict__ A, const __bf16* __restrict__ WoutT,
    const float* __restrict__ bout, float* __restrict__ out)
{
    __shared__ __attribute__((aligned(16))) __bf16 as[4 * 12 * 512];   // frags [mt][kb][slot][8]
    const int blk = blockIdx.x, tid = threadIdx.x;
    const int wave = tid >> 6, lane = tid & 63;
    const int l15 = lane & 15, l4 = lane >> 4;

    const __bf16* Ab = A + (size_t)blk * 64 * CDIM;
    for (int i = tid; i < 64 * CDIM / 8; i += 256) {
        int4 ld = reinterpret_cast<const int4*>(Ab)[i];
        int e = i * 8;
        int row = e / CDIM, c = e % CDIM;
        int mt = row >> 4, kb = c >> 5;
        int lp = (row & 15) + 16 * ((c & 31) >> 3);
        int slot = lp ^ (kb & 7);
        *reinterpret_cast<int4*>(&as[((mt * 12 + kb) * 64 + slot) * 8]) = ld;
    }
    __syncthreads();

    f32x4 acc[6][4] = {};
    for (int kb = 0; kb < 12; ++kb) {
        int slot = lane ^ (kb & 7);
        bf16x8 af[4];
#pragma unroll
        for (int mt = 0; mt < 4; ++mt)
            af[mt] = *reinterpret_cast<const bf16x8*>(&as[((mt * 12 + kb) * 64 + slot) * 8]);
#pragma unroll
        for (int j = 0; j < 6; ++j) {
            int col = (wave * 6 + j) * 16 + l15;
            bf16x8 bf = *reinterpret_cast<const bf16x8*>(WoutT + (size_t)col * CDIM + kb * 32 + l4 * 8);
#pragma unroll
            for (int mt = 0; mt < 4; ++mt)
                acc[j][mt] = __builtin_amdgcn_mfma_f32_16x16x32_bf16(af[mt], bf, acc[j][mt], 0, 0, 0);
        }
    }
#pragma unroll
    for (int j = 0; j < 6; ++j) {
        int col = (wave * 6 + j) * 16 + l15;
        float bias = bout[col];
#pragma unroll
        for (int mt = 0; mt < 4; ++mt) {
#pragma unroll
            for (int r = 0; r < 4; ++r) {
                size_t row = (size_t)blk * 64 + mt * 16 + l4 * 4 + r;
                out[row * CDIM + col] = acc[j][mt][r] + bias;
            }
        }
    }
}

// ---------------- launch ----------------

extern "C" void kernel_launch(void* const* d_in, const int* in_sizes, int n_in,
                              void* d_out, int out_size, void* d_ws, size_t ws_size,
                              hipStream_t stream) {
    (void)n_in; (void)out_size; (void)ws_size;
    const float* x    = (const float*)d_in[0];
    const float* mask = (const float*)d_in[1];
    const float* Wqkv = (const float*)d_in[2];
    const float* bqkv = (const float*)d_in[3];
    const float* Wout = (const float*)d_in[4];
    const float* bout = (const float*)d_in[5];
    const float* rpb  = (const float*)d_in[6];
    const int*   rel  = (const int*)d_in[7];

    const int B = in_sizes[0] / (NTOK * CDIM);   // 4096

    char* ws = (char*)d_ws;
    __bf16* WqkvT   = (__bf16*)(ws + OFF_WQKVT);
    __bf16* WoutT   = (__bf16*)(ws + OFF_WOUTT);
    float*  addend  = (float*)(ws + OFF_ADDEND);
    __bf16* attnout = (__bf16*)(ws + OFF_ATTNOUT);
    float*  out     = (float*)d_out;

    prep_weights<<<(NQKV * CDIM + 255) / 256, 256, 0, stream>>>(Wqkv, Wout, WqkvT, WoutT);
    prep_addend<<<(NWIN * HEADS * NTOK * NTOK + 255) / 256, 256, 0, stream>>>(rpb, rel, mask, addend);
    fused_qkv_attn<<<B, 512, 0, stream>>>(x, bqkv, WqkvT, addend, attnout);
    out_proj<<<(B * NTOK) / 64, 256, 0, stream>>>(attnout, WoutT, bout, out);
}